// Round 6
// baseline (3970.333 us; speedup 1.0000x reference)
//
#include <hip/hip_runtime.h>

#define NB 128      // batch
#define NH 1024     // hidden
#define NS 256      // conditioning sequence length
#define NF 8        // forecast length
#define NBLK 192    // persistent blocks: 64 L0 | 64 GI | 64 GH
#define NTH 512     // 8 waves
#define AG  __HIP_MEMORY_SCOPE_AGENT

// barrier line indices (uint32 units; distinct 128B lines)
#define GLOBL 0            // MALL line: touched ONLY by 8 rank0s
#define INITL 128
#define XCNT  192          // +32*xcd  (init registration)
#define XARR  512          // +32*xcd  (XCD-local L2: arrival)
#define XREL  768          // +32*xcd  (XCD-local L2: release)
#define XCPY  1024         // +32*xcd  (XCD-local L2: copy barrier)

typedef _Float16 half_t;
typedef _Float16 f16x8 __attribute__((ext_vector_type(8)));
typedef float f32x4 __attribute__((ext_vector_type(4)));
typedef unsigned long long u64;

struct GP {
    const float *x, *hin, *Wih0, *Whh0, *bih0, *bhh0, *Wih1, *Whh1, *bih1, *bhh1, *fcw, *fcb;
    float *gib0, *gib1, *ys, *out;
    half_t *h0b0, *h0b1, *h1b0, *h1b1;
    char *reg;            // XCD-private A regions: [8 xcd][2 slot][h0 256K | h1 256K]
    unsigned *bar;
};

__device__ __forceinline__ float fast_sigmoid(float x) { return 1.0f / (1.0f + __expf(-x)); }
__device__ __forceinline__ float fast_tanh(float x) {
    float e = __expf(2.0f * x);
    return (e - 1.0f) / (e + 1.0f);
}

// ---- agent-scope (sc1 / MALL) accesses ----
__device__ __forceinline__ u64 ldu64(const void* p) {
    return __hip_atomic_load((const u64*)p, __ATOMIC_RELAXED, AG);
}
__device__ __forceinline__ void stu64(void* p, u64 v) {
    __hip_atomic_store((u64*)p, v, __ATOMIC_RELAXED, AG);
}
__device__ __forceinline__ float ldf32(const float* p) {
    return __hip_atomic_load(p, __ATOMIC_RELAXED, AG);
}
__device__ __forceinline__ unsigned aadd(unsigned* p, unsigned v) {
    return __hip_atomic_fetch_add(p, v, __ATOMIC_RELAXED, AG);
}
__device__ __forceinline__ unsigned ald(const unsigned* p) {
    return __hip_atomic_load(p, __ATOMIC_RELAXED, AG);
}

// ---- XCD-local (no sc1 -> executes in the local XCD's L2) atomics ----
__device__ __forceinline__ void l2add(unsigned* p, unsigned v) {
    asm volatile("global_atomic_add %0, %1, off" :: "v"(p), "v"(v) : "memory");
}
__device__ __forceinline__ unsigned l2add_rtn(unsigned* p, unsigned v) {
    unsigned ret;
    asm volatile("global_atomic_add %0, %1, %2, off sc0\n\ts_waitcnt vmcnt(0)"
                 : "=v"(ret) : "v"(p), "v"(v) : "memory");
    return ret;
}

// ---------------- init: f16 copies of h0 + ys seeded with fc bias ----------------
__global__ void k_init(const float* __restrict__ hin, half_t* __restrict__ h0h,
                       half_t* __restrict__ h1h, const float* __restrict__ fcb,
                       float* __restrict__ ys) {
    int i = blockIdx.x * 256 + threadIdx.x;   // 512 blocks -> 131072 = NB*NH
    h0h[i] = (half_t)hin[i];
    h1h[i] = (half_t)hin[NB * NH + i];
    if (blockIdx.x == 0) {
        float fb = fcb[0];
        for (int j = threadIdx.x; j < NF * NB; j += 256) ys[j] = fb;
    }
}

// ---------------- persistent GRU kernel ----------------
__global__ __launch_bounds__(NTH)
void k_gru(GP p) {
    extern __shared__ char lds[];   // [0,96K) W swz | [96K..) h master 8K | meta @104K
    const int tid = threadIdx.x;
    const int l   = tid & 63;
    const int wv  = tid >> 6;               // 0..7
    const int bid = blockIdx.x;
    const int role = (bid < 64) ? 0 : (bid < 128 ? 1 : 2);
    const int bc   = bid & 63;
    const int colbase = bc * 16;
    float* hl  = (float*)(lds + 98304);     // block-private h master (roles 0,2)
    int* meta  = (int*)(lds + 106496);
    unsigned* bar = p.bar;

    // ---- one-time: W slice (3 gates x 16 cols x 1024 k) f32 -> f16 into LDS
    {
        const float* Wsrc = (role == 0) ? p.Whh0 : ((role == 1) ? p.Wih1 : p.Whh1);
        for (int i = tid; i < 12288; i += NTH) {   // float4 chunks: 48 rows x 256
            int row = i >> 8, j = i & 255;
            int g = row >> 4, r = row & 15;
            float4 v = *(const float4*)(Wsrc + (size_t)(g * NH + colbase + r) * NH + j * 4);
            union { half_t h[4]; uint2 u; } cv;
            cv.h[0] = (half_t)v.x; cv.h[1] = (half_t)v.y;
            cv.h[2] = (half_t)v.z; cv.h[3] = (half_t)v.w;
            *(uint2*)(lds + (row * 2048 + ((j * 8) ^ ((row & 7) << 4)))) = cv.u;
        }
        if (role != 1) {   // h master f32 into LDS
            const float* hsrc = p.hin + (role == 2 ? NB * NH : 0);
            for (int i = tid; i < NB * 16; i += NTH) {
                int b = i >> 4, cl = i & 15;
                hl[i] = hsrc[(size_t)b * NH + colbase + cl];
            }
        }
    }

    // ---- one-time: XCD discovery + registration + flat init barrier (AG scope)
    if (tid == 0) {
        unsigned x;
        asm volatile("s_getreg_b32 %0, hwreg(HW_REG_XCC_ID)" : "=s"(x));
        x &= 7;
        unsigned r = aadd(bar + XCNT + x * 32, 1u);
        asm volatile("s_waitcnt vmcnt(0)" ::: "memory");
        aadd(bar + INITL, 1u);
        while (ald(bar + INITL) < NBLK) __builtin_amdgcn_s_sleep(1);
        int nn = 0, cnt = 0;
        for (int k = 0; k < 8; ++k) {
            unsigned c = ald(bar + XCNT + k * 32);
            if (c) ++cnt;
            if (k == (int)x) nn = (int)c;
        }
        meta[0] = (int)x; meta[1] = (int)r; meta[2] = nn; meta[3] = cnt;
    }
    __syncthreads();
    const int xcd_  = meta[0];
    const int rank_ = meta[1];
    const int n_    = meta[2];
    const int nx_   = meta[3];

    // ---- per-role constants
    const int cloc = l & 15;
    const int c = colbase + cloc;
    float bi_[3] = {0,0,0}, bh_[3] = {0,0,0}, wx_[3] = {0,0,0}, fcwv = 0.f;
    if (role == 0) {
        #pragma unroll
        for (int g = 0; g < 3; ++g) {
            bi_[g] = p.bih0[g * NH + c]; bh_[g] = p.bhh0[g * NH + c];
            wx_[g] = p.Wih0[g * NH + c];
        }
    } else if (role == 2) {
        #pragma unroll
        for (int g = 0; g < 3; ++g) {
            bi_[g] = p.bih1[g * NH + c]; bh_[g] = p.bhh1[g * NH + c];
        }
        fcwv = p.fcw[c];
    }

    const int rbase[3] = { cloc * 2048, (16 + cloc) * 2048, (32 + cloc) * 2048 };
    const int rmask = (cloc & 7) << 4;
    const int kb0 = (l >> 4) << 4;                 // byte offset of lane's k-chunk
    const int arow = wv * 16 + cloc;               // A row this lane needs
    const int b0base = wv * 16 + ((l >> 4) << 2);  // first output batch row
    const int aloff = arow * 2048 + ((l >> 4) << 4);   // byte offset in linear [128][1024] f16

    // ---- global barrier: local arrival -> 8-contender MALL line -> local release
    auto gbar = [&](unsigned t) {
        asm volatile("s_waitcnt vmcnt(0)" ::: "memory");   // every wave drains its stores
        __syncthreads();
        if (tid == 0) {
            l2add(bar + XARR + xcd_ * 32, 1u);
            if (rank_ == 0) {
                while (l2add_rtn(bar + XARR + xcd_ * 32, 0u) < (unsigned)n_ * t)
                    __builtin_amdgcn_s_sleep(1);
                aadd(bar + GLOBL, 1u);
                while (aadd(bar + GLOBL, 0u) < (unsigned)nx_ * t)
                    __builtin_amdgcn_s_sleep(1);
                l2add(bar + XREL + xcd_ * 32, 1u);
            } else {
                while (l2add_rtn(bar + XREL + xcd_ * 32, 0u) < t)
                    __builtin_amdgcn_s_sleep(1);
            }
        }
        __syncthreads();
        asm volatile("buffer_inv" ::: "memory");   // L1-only invalidate
    };

    // ---- per-phase: linear copy of fresh h into this XCD's region
    // 32768 x 16B chunks: [0,16384)=h0, [16384,32768)=h1
    auto xcopy = [&](const half_t* h0s, const half_t* h1s, int slot) {
        char* dst = p.reg + ((size_t)(xcd_ * 2 + slot)) * 524288;
        const int base = rank_ * NTH + tid;
        const int stride = n_ * NTH;
        uint4 v0, v1, v2, v3;
        int i0 = base, i1 = base + stride, i2 = base + 2 * stride, i3 = base + 3 * stride;
        const char* s0 = (i0 < 16384) ? (const char*)h0s + (size_t)i0 * 16 : (const char*)h1s + (size_t)(i0 - 16384) * 16;
        const char* s1 = (i1 < 16384) ? (const char*)h0s + (size_t)i1 * 16 : (const char*)h1s + (size_t)(i1 - 16384) * 16;
        const char* s2 = (i2 < 16384) ? (const char*)h0s + (size_t)i2 * 16 : (const char*)h1s + (size_t)(i2 - 16384) * 16;
        const char* s3 = (i3 < 16384) ? (const char*)h0s + (size_t)i3 * 16 : (const char*)h1s + (size_t)(i3 - 16384) * 16;
        if (i0 < 32768) asm volatile("global_load_dwordx4 %0, %1, off sc0 sc1" : "=v"(v0) : "v"(s0) : "memory");
        if (i1 < 32768) asm volatile("global_load_dwordx4 %0, %1, off sc0 sc1" : "=v"(v1) : "v"(s1) : "memory");
        if (i2 < 32768) asm volatile("global_load_dwordx4 %0, %1, off sc0 sc1" : "=v"(v2) : "v"(s2) : "memory");
        if (i3 < 32768) asm volatile("global_load_dwordx4 %0, %1, off sc0 sc1" : "=v"(v3) : "v"(s3) : "memory");
        __builtin_amdgcn_sched_barrier(0);
        asm volatile("s_waitcnt vmcnt(0)" ::: "memory");
        __builtin_amdgcn_sched_barrier(0);
        if (i0 < 32768) *(uint4*)(dst + (size_t)i0 * 16) = v0;
        if (i1 < 32768) *(uint4*)(dst + (size_t)i1 * 16) = v1;
        if (i2 < 32768) *(uint4*)(dst + (size_t)i2 * 16) = v2;
        if (i3 < 32768) *(uint4*)(dst + (size_t)i3 * 16) = v3;
    };
    auto csync = [&](unsigned ct) {   // XCD-local copy barrier (local L2 atomics)
        asm volatile("s_waitcnt vmcnt(0)" ::: "memory");
        __syncthreads();
        if (tid == 0) {
            l2add(bar + XCPY + xcd_ * 32, 1u);
            while (l2add_rtn(bar + XCPY + xcd_ * 32, 0u) < (unsigned)n_ * ct)
                __builtin_amdgcn_s_sleep(1);
        }
        __syncthreads();
    };

    // ---- GEMM: A from XCD region (plain cached loads, linear layout), W from LDS
    auto do_gemm = [&](const char* regA, f32x4 (&acc)[3]) {
        const char* ap = regA + aloff;
        #pragma unroll 8
        for (int ks = 0; ks < 32; ++ks) {
            f16x8 a = *(const f16x8*)(ap + ks * 64);
            int kb = ks * 64 + kb0;
            #pragma unroll
            for (int g = 0; g < 3; ++g) {
                f16x8 bf = *(const f16x8*)(lds + rbase[g] + (kb ^ rmask));
                acc[g] = __builtin_amdgcn_mfma_f32_16x16x32_f16(a, bf, acc[g], 0, 0, 0);
            }
        }
    };

    // pack 4 lanes' f16 h-values into one u64, store coherent (sc1)
    auto pack_store_h = [&](half_t* hw, int b, float hn) {
        unsigned v = (unsigned)__builtin_bit_cast(unsigned short, (half_t)hn);
        unsigned o = __shfl_xor(v, 1);
        unsigned pair = (l & 1) ? (o | (v << 16)) : (v | (o << 16));
        unsigned p2 = __shfl_xor(pair, 2);
        u64 quad = (l & 2) ? (((u64)pair << 32) | p2) : ((u64)pair | ((u64)p2 << 32));
        if ((l & 3) == 0) stu64(hw + (size_t)b * NH + (c & ~3), quad);
    };

    auto l0_epi = [&](const float xv[4], f32x4 (&acc)[3], half_t* hw) {
        #pragma unroll
        for (int q = 0; q < 4; ++q) {
            int b = b0base + q;
            float gh0 = acc[0][q] + bh_[0];
            float gh1 = acc[1][q] + bh_[1];
            float gh2 = acc[2][q] + bh_[2];
            float r_ = fast_sigmoid(xv[q] * wx_[0] + bi_[0] + gh0);
            float z_ = fast_sigmoid(xv[q] * wx_[1] + bi_[1] + gh1);
            float n_2 = fast_tanh(xv[q] * wx_[2] + bi_[2] + r_ * gh2);
            float hp = hl[b * 16 + cloc];
            float hn = (1.0f - z_) * n_2 + z_ * hp;
            hl[b * 16 + cloc] = hn;
            pack_store_h(hw, b, hn);
        }
    };

    auto gi_epi = [&](f32x4 (&acc)[3], float* gw) {
        #pragma unroll
        for (int g = 0; g < 3; ++g) {
            union { f32x4 v; u64 u[2]; } t; t.v = acc[g];
            float* dst = gw + ((size_t)g * NH + c) * NB + b0base;
            stu64(dst, t.u[0]);
            stu64(dst + 2, t.u[1]);
        }
    };

    // role-2 epilogue; optionally accumulates fc partial dot into ydst (device atomics)
    auto gh_epi = [&](f32x4 (&acc)[3], const f32x4 gv[3], half_t* hw, float* ydst) {
        float hn4[4];
        #pragma unroll
        for (int q = 0; q < 4; ++q) {
            int b = b0base + q;
            float gh0 = acc[0][q] + bh_[0];
            float gh1 = acc[1][q] + bh_[1];
            float gh2 = acc[2][q] + bh_[2];
            float r_ = fast_sigmoid(gv[0][q] + bi_[0] + gh0);
            float z_ = fast_sigmoid(gv[1][q] + bi_[1] + gh1);
            float n_2 = fast_tanh(gv[2][q] + bi_[2] + r_ * gh2);
            float hp = hl[b * 16 + cloc];
            float hn = (1.0f - z_) * n_2 + z_ * hp;
            hl[b * 16 + cloc] = hn;
            hn4[q] = hn;
            pack_store_h(hw, b, hn);
        }
        if (ydst) {
            float s0 = hn4[0] * fcwv, s1 = hn4[1] * fcwv, s2 = hn4[2] * fcwv, s3 = hn4[3] * fcwv;
            #pragma unroll
            for (int m = 1; m < 16; m <<= 1) {
                s0 += __shfl_xor(s0, m); s1 += __shfl_xor(s1, m);
                s2 += __shfl_xor(s2, m); s3 += __shfl_xor(s3, m);
            }
            if (cloc == 0) {
                atomicAdd(ydst + b0base, s0);
                atomicAdd(ydst + b0base + 1, s1);
                atomicAdd(ydst + b0base + 2, s2);
                atomicAdd(ydst + b0base + 3, s3);
            }
        }
    };

    auto load_gi = [&](const float* gr, f32x4 (&gv)[3]) {
        #pragma unroll
        for (int g = 0; g < 3; ++g) {
            union { f32x4 v; u64 u[2]; } t;
            const float* src = gr + ((size_t)g * NH + c) * NB + b0base;
            t.u[0] = ldu64(src);
            t.u[1] = ldu64(src + 2);
            gv[g] = t.v;
        }
    };

    unsigned tgt = 0, ctgt = 0;
    int cur0 = 0, cur1 = 0, gcur = 0;
    f32x4 zero4 = {0.f, 0.f, 0.f, 0.f};

    auto COPY = [&]() {   // stage current read-buffers into region, return slot base
        ++ctgt;
        int slot = (int)(ctgt & 1);
        xcopy(cur0 ? p.h0b1 : p.h0b0, cur1 ? p.h1b1 : p.h1b0, slot);
        csync(ctgt);
        return p.reg + ((size_t)(xcd_ * 2 + slot)) * 524288;
    };

    // ---- conditioning: phases 0 .. NS+1 (3-stage pipeline); y0 fused at ph==NS+1
    for (int ph = 0; ph < NS + 2; ++ph) {
        float xv[4];
        f32x4 gv[3];
        if (role == 0 && ph < NS) {         // plain cached loads (x is read-only)
            #pragma unroll
            for (int q = 0; q < 4; ++q) xv[q] = p.x[(size_t)(b0base + q) * NS + ph];
        } else if (role == 2 && ph >= 2) {  // sc1 prefetch, hides under the copy
            load_gi(gcur ? p.gib1 : p.gib0, gv);
        }
        const char* regB = COPY();
        if (role == 0 && ph < NS) {
            f32x4 acc[3] = {zero4, zero4, zero4};
            do_gemm(regB, acc);
            l0_epi(xv, acc, cur0 ? p.h0b0 : p.h0b1);
        } else if (role == 1 && ph >= 1 && ph <= NS) {
            f32x4 acc[3] = {zero4, zero4, zero4};
            do_gemm(regB, acc);
            gi_epi(acc, gcur ? p.gib0 : p.gib1);
        } else if (role == 2 && ph >= 2) {
            f32x4 acc[3] = {zero4, zero4, zero4};
            do_gemm(regB + 262144, acc);
            gh_epi(acc, gv, cur1 ? p.h1b0 : p.h1b1, (ph == NS + 1) ? p.ys : nullptr);
        }
        ++tgt; gbar(tgt);
        if (ph < NS) cur0 ^= 1;
        if (ph >= 1 && ph <= NS) gcur ^= 1;
        if (ph >= 2) cur1 ^= 1;
    }

    // ---- forecast: 7 autoregressive steps, 3 phases each (L0 -> GI -> GH+fc)
    for (int i = 1; i < NF; ++i) {
        float xv[4];
        if (role == 0) {   // sc1 prefetch of ys before copy
            #pragma unroll
            for (int q = 0; q < 4; ++q) xv[q] = ldf32(p.ys + (i - 1) * NB + b0base + q);
        }
        const char* regB = COPY();
        if (role == 0) {
            f32x4 acc[3] = {zero4, zero4, zero4};
            do_gemm(regB, acc);
            l0_epi(xv, acc, cur0 ? p.h0b0 : p.h0b1);
        }
        ++tgt; gbar(tgt); cur0 ^= 1;

        regB = COPY();
        if (role == 1) {
            f32x4 acc[3] = {zero4, zero4, zero4};
            do_gemm(regB, acc);
            gi_epi(acc, gcur ? p.gib0 : p.gib1);
        }
        ++tgt; gbar(tgt); gcur ^= 1;

        {
            f32x4 gv[3];
            if (role == 2) load_gi(gcur ? p.gib1 : p.gib0, gv);
            regB = COPY();
            if (role == 2) {
                f32x4 acc[3] = {zero4, zero4, zero4};
                do_gemm(regB + 262144, acc);
                gh_epi(acc, gv, cur1 ? p.h1b0 : p.h1b1, p.ys + i * NB);
            }
        }
        ++tgt; gbar(tgt); cur1 ^= 1;
    }

    // ---- final output: mean of forecasts + h_final export from LDS
    if (bid == 0 && tid < NB) {
        float s = 0.0f;
        #pragma unroll
        for (int k = 0; k < NF; ++k) s += ldf32(p.ys + k * NB + tid);
        p.out[tid] = s * 0.125f;
    }
    if (role != 1) {
        float* ob = p.out + NB + (role == 2 ? (size_t)NB * NH : 0);
        for (int i = tid; i < NB * 16; i += NTH) {
            int b = i >> 4, cl = i & 15;
            ob[(size_t)b * NH + colbase + cl] = hl[i];
        }
    }
}

extern "C" void kernel_launch(void* const* d_in, const int* in_sizes, int n_in,
                              void* d_out, int out_size, void* d_ws, size_t ws_size,
                              hipStream_t stream)
{
    GP p;
    p.x    = (const float*)d_in[0];
    p.hin  = (const float*)d_in[1];
    p.Wih0 = (const float*)d_in[2];
    p.Whh0 = (const float*)d_in[3];
    p.bih0 = (const float*)d_in[4];
    p.bhh0 = (const float*)d_in[5];
    p.Wih1 = (const float*)d_in[6];
    p.Whh1 = (const float*)d_in[7];
    p.bih1 = (const float*)d_in[8];
    p.bhh1 = (const float*)d_in[9];
    p.fcw  = (const float*)d_in[10];
    p.fcb  = (const float*)d_in[11];
    p.out  = (float*)d_out;

    char* ws = (char*)d_ws;
    p.bar  = (unsigned*)ws;                      ws += 8192;
    p.h0b0 = (half_t*)ws;                        ws += 262144;
    p.h0b1 = (half_t*)ws;                        ws += 262144;
    p.h1b0 = (half_t*)ws;                        ws += 262144;
    p.h1b1 = (half_t*)ws;                        ws += 262144;
    p.gib0 = (float*)ws;                         ws += 1572864;
    p.gib1 = (float*)ws;                         ws += 1572864;
    p.ys   = (float*)ws;                         ws += 4096;
    ws = (char*)(((size_t)ws + 4095) & ~(size_t)4095);
    p.reg  = ws;                                 ws += 8 * 2 * 524288;   // 8 MiB

    hipMemsetAsync(p.bar, 0, 8192, stream);
    k_init<<<512, 256, 0, stream>>>(p.hin, p.h0b0, p.h1b0, p.fcb, p.ys);

    void* args[] = { &p };
    if (hipLaunchCooperativeKernel((void*)k_gru, dim3(NBLK), dim3(NTH), args,
                                   106752, stream) != hipSuccess) {
        (void)hipGetLastError();
        // fallback: 192 blocks @ ~104KiB LDS = 1 block/CU on 256 CUs -> co-resident
        k_gru<<<dim3(NBLK), dim3(NTH), 106752, stream>>>(p);
    }
}

// Round 9
// 3720.741 us; speedup vs baseline: 1.0671x; 1.0671x over previous
//
#include <hip/hip_runtime.h>

#define NB 128      // batch
#define NH 1024     // hidden
#define NS 256      // conditioning sequence length
#define NF 8        // forecast length
#define NBLK 192    // persistent blocks: 64 L0 | 64 GI | 64 GH
#define NTH 512     // 8 waves
#define AG  __HIP_MEMORY_SCOPE_AGENT

// barrier line indices (uint32 units; distinct >=128B-separated lines)
#define GLOBL 0            // MALL line: ONLY 8 rank0s add; nobody polls (last-detect)
#define RELL  64           // MALL line: 1 adder, 192 atomic-load pollers (R5-proven)
#define INITL 128
#define XCNT  192          // +32*xcd  (init registration)
#define XARR  512          // +32*xcd  (XCD-local L2: arrival, atomic RMW poll)
#define XCPY  1024         // +32*xcd  (XCD-local L2: copy barrier, atomic RMW poll)

typedef _Float16 half_t;
typedef _Float16 f16x8 __attribute__((ext_vector_type(8)));
typedef float f32x4 __attribute__((ext_vector_type(4)));
typedef unsigned long long u64;

struct GP {
    const float *x, *hin, *Wih0, *Whh0, *bih0, *bhh0, *Wih1, *Whh1, *bih1, *bhh1, *fcw, *fcb;
    float *gib0, *gib1, *ypart, *out;
    half_t *h0b0, *h0b1, *h1b0, *h1b1;
    char *reg;            // XCD-private A regions: [8 xcd][2 slot][h0 256K | h1 256K]
    unsigned *bar;
};

__device__ __forceinline__ float fast_sigmoid(float x) { return 1.0f / (1.0f + __expf(-x)); }
__device__ __forceinline__ float fast_tanh(float x) {
    float e = __expf(2.0f * x);
    return (e - 1.0f) / (e + 1.0f);
}

// ---- agent-scope (sc1 / MALL) accesses ----
__device__ __forceinline__ u64 ldu64(const void* p) {
    return __hip_atomic_load((const u64*)p, __ATOMIC_RELAXED, AG);
}
__device__ __forceinline__ void stu64(void* p, u64 v) {
    __hip_atomic_store((u64*)p, v, __ATOMIC_RELAXED, AG);
}
__device__ __forceinline__ float ldf32(const float* p) {
    return __hip_atomic_load(p, __ATOMIC_RELAXED, AG);
}
__device__ __forceinline__ void stf32(float* p, float v) {
    __hip_atomic_store(p, v, __ATOMIC_RELAXED, AG);
}
__device__ __forceinline__ unsigned aadd(unsigned* p, unsigned v) {
    return __hip_atomic_fetch_add(p, v, __ATOMIC_RELAXED, AG);
}
__device__ __forceinline__ unsigned ald(const unsigned* p) {   // sc1 atomic load (MALL-fresh)
    return __hip_atomic_load(p, __ATOMIC_RELAXED, AG);
}

// ---- XCD-local atomics (no sc1 -> execute in the local XCD's L2; always fresh) ----
__device__ __forceinline__ void l2add(unsigned* p, unsigned v) {
    asm volatile("global_atomic_add %0, %1, off" :: "v"(p), "v"(v) : "memory");
}
__device__ __forceinline__ unsigned l2add_rtn(unsigned* p, unsigned v) {
    unsigned ret;
    asm volatile("global_atomic_add %0, %1, %2, off sc0\n\ts_waitcnt vmcnt(0)"
                 : "=v"(ret) : "v"(p), "v"(v) : "memory");
    return ret;
}

// ---------------- init: f16 copies of initial hidden state ----------------
__global__ void k_init(const float* __restrict__ hin, half_t* __restrict__ h0h,
                       half_t* __restrict__ h1h) {
    int i = blockIdx.x * 256 + threadIdx.x;   // 512 blocks -> 131072 = NB*NH
    h0h[i] = (half_t)hin[i];
    h1h[i] = (half_t)hin[NB * NH + i];
}

// ---------------- persistent GRU kernel ----------------
__global__ __launch_bounds__(NTH)
void k_gru(GP p) {
    extern __shared__ char lds[];   // [0,96K) W swz | [96K..) h master 8K | meta @104K
    const int tid = threadIdx.x;
    const int l   = tid & 63;
    const int wv  = tid >> 6;               // 0..7
    const int bid = blockIdx.x;
    const int role = (bid < 64) ? 0 : (bid < 128 ? 1 : 2);
    const int bc   = bid & 63;
    const int colbase = bc * 16;
    float* hl  = (float*)(lds + 98304);     // block-private h master (roles 0,2)
    int* meta  = (int*)(lds + 106496);
    unsigned* bar = p.bar;

    // ---- one-time: W slice (3 gates x 16 cols x 1024 k) f32 -> f16 into LDS
    {
        const float* Wsrc = (role == 0) ? p.Whh0 : ((role == 1) ? p.Wih1 : p.Whh1);
        for (int i = tid; i < 12288; i += NTH) {   // float4 chunks: 48 rows x 256
            int row = i >> 8, j = i & 255;
            int g = row >> 4, r = row & 15;
            float4 v = *(const float4*)(Wsrc + (size_t)(g * NH + colbase + r) * NH + j * 4);
            union { half_t h[4]; uint2 u; } cv;
            cv.h[0] = (half_t)v.x; cv.h[1] = (half_t)v.y;
            cv.h[2] = (half_t)v.z; cv.h[3] = (half_t)v.w;
            *(uint2*)(lds + (row * 2048 + ((j * 8) ^ ((row & 7) << 4)))) = cv.u;
        }
        if (role != 1) {   // h master f32 into LDS
            const float* hsrc = p.hin + (role == 2 ? NB * NH : 0);
            for (int i = tid; i < NB * 16; i += NTH) {
                int b = i >> 4, cl = i & 15;
                hl[i] = hsrc[(size_t)b * NH + colbase + cl];
            }
        }
    }

    // ---- one-time: XCD discovery + registration + flat init barrier (AG scope)
    if (tid == 0) {
        unsigned x;
        asm volatile("s_getreg_b32 %0, hwreg(HW_REG_XCC_ID)" : "=s"(x));
        x &= 7;
        unsigned r = aadd(bar + XCNT + x * 32, 1u);
        asm volatile("s_waitcnt vmcnt(0)" ::: "memory");
        aadd(bar + INITL, 1u);
        while (ald(bar + INITL) < NBLK) __builtin_amdgcn_s_sleep(1);
        int nn = 0, cnt = 0;
        for (int k = 0; k < 8; ++k) {
            unsigned c = ald(bar + XCNT + k * 32);
            if (c) ++cnt;
            if (k == (int)x) nn = (int)c;
        }
        meta[0] = (int)x; meta[1] = (int)r; meta[2] = nn; meta[3] = cnt;
    }
    __syncthreads();
    const int xcd_  = meta[0];
    const int rank_ = meta[1];
    const int n_    = meta[2];
    const int nx_   = meta[3];

    // ---- per-role constants
    const int cloc = l & 15;
    const int c = colbase + cloc;
    float bi_[3] = {0,0,0}, bh_[3] = {0,0,0}, wx_[3] = {0,0,0}, fcwv = 0.f, fcb_ = 0.f;
    if (role == 0) {
        #pragma unroll
        for (int g = 0; g < 3; ++g) {
            bi_[g] = p.bih0[g * NH + c]; bh_[g] = p.bhh0[g * NH + c];
            wx_[g] = p.Wih0[g * NH + c];
        }
        fcb_ = p.fcb[0];
    } else if (role == 2) {
        #pragma unroll
        for (int g = 0; g < 3; ++g) {
            bi_[g] = p.bih1[g * NH + c]; bh_[g] = p.bhh1[g * NH + c];
        }
        fcwv = p.fcw[c];
    }

    const int rbase[3] = { cloc * 2048, (16 + cloc) * 2048, (32 + cloc) * 2048 };
    const int rmask = (cloc & 7) << 4;
    const int kb0 = (l >> 4) << 4;                 // byte offset of lane's k-chunk
    const int arow = wv * 16 + cloc;               // A row this lane needs
    const int b0base = wv * 16 + ((l >> 4) << 2);  // first output batch row
    const int aloff = (l >> 4) * 2048 + arow * 16; // lane offset in region [kq][row] layout

    // ---- global barrier (R5-proven): local RMW arrive -> rank0 RMW-poll local line
    //      -> aadd GLOBL (last-detect via returned old; nobody polls GLOBL)
    //      -> bump RELL -> 192 atomic-load pollers on RELL
    auto gbar = [&](unsigned t) {
        __syncthreads();   // compiler drains vmcnt before s_barrier -> stores MALL-visible
        if (tid == 0) {
            l2add(bar + XARR + xcd_ * 32, 1u);
            if (rank_ == 0) {
                while (l2add_rtn(bar + XARR + xcd_ * 32, 0u) < (unsigned)n_ * t)
                    __builtin_amdgcn_s_sleep(1);
                unsigned old = aadd(bar + GLOBL, 1u);
                if (old == (unsigned)nx_ * t - 1u) aadd(bar + RELL, 1u);
            }
            while (ald(bar + RELL) < t) __builtin_amdgcn_s_sleep(1);
        }
        __syncthreads();
        asm volatile("buffer_inv" ::: "memory");   // L1-only invalidate
    };

    // ---- per-phase: pull fresh h into this XCD's region (transposed [kq][row])
    auto xcopy = [&](const half_t* h0s, const half_t* h1s, int slot) {
        char* dst = p.reg + ((size_t)(xcd_ * 2 + slot)) * 524288;
        for (int idx = rank_ * NTH + tid; idx < 32768; idx += n_ * NTH) {
            int which = idx >> 14, kq = (idx >> 7) & 127, row = idx & 127;
            const half_t* s = (which ? h1s : h0s) + row * 1024 + kq * 8;
            union { u64 u[2]; uint4 v; } t;
            t.u[0] = ldu64(s);
            t.u[1] = ldu64(s + 4);
            *(uint4*)(dst + which * 262144 + (size_t)(kq * 128 + row) * 16) = t.v;
        }
    };
    auto csync = [&](unsigned ct) {   // XCD-local copy barrier: RMW arrive, RMW poll
        __syncthreads();
        if (tid == 0) {
            l2add(bar + XCPY + xcd_ * 32, 1u);
            while (l2add_rtn(bar + XCPY + xcd_ * 32, 0u) < (unsigned)n_ * ct)
                __builtin_amdgcn_s_sleep(1);
        }
        __syncthreads();
    };

    // ---- GEMM: A from XCD region (plain cached loads), W from LDS
    auto do_gemm = [&](const char* regA, f32x4 (&acc)[3]) {
        const char* ap = regA + aloff;
        #pragma unroll 16
        for (int ks = 0; ks < 32; ++ks) {
            f16x8 a = *(const f16x8*)(ap + (size_t)ks * 8192);
            int kb = ks * 64 + kb0;
            #pragma unroll
            for (int g = 0; g < 3; ++g) {
                f16x8 bf = *(const f16x8*)(lds + rbase[g] + (kb ^ rmask));
                acc[g] = __builtin_amdgcn_mfma_f32_16x16x32_f16(a, bf, acc[g], 0, 0, 0);
            }
        }
    };

    // pack 4 lanes' f16 h-values into one u64, store coherent (sc1)
    auto pack_store_h = [&](half_t* hw, int b, float hn) {
        unsigned v = (unsigned)__builtin_bit_cast(unsigned short, (half_t)hn);
        unsigned o = __shfl_xor(v, 1);
        unsigned pair = (l & 1) ? (o | (v << 16)) : (v | (o << 16));
        unsigned p2 = __shfl_xor(pair, 2);
        u64 quad = (l & 2) ? (((u64)pair << 32) | p2) : ((u64)pair | ((u64)p2 << 32));
        if ((l & 3) == 0) stu64(hw + (size_t)b * NH + (c & ~3), quad);
    };

    auto l0_epi = [&](const float xv[4], f32x4 (&acc)[3], half_t* hw) {
        #pragma unroll
        for (int q = 0; q < 4; ++q) {
            int b = b0base + q;
            float gh0 = acc[0][q] + bh_[0];
            float gh1 = acc[1][q] + bh_[1];
            float gh2 = acc[2][q] + bh_[2];
            float r_ = fast_sigmoid(xv[q] * wx_[0] + bi_[0] + gh0);
            float z_ = fast_sigmoid(xv[q] * wx_[1] + bi_[1] + gh1);
            float n_2 = fast_tanh(xv[q] * wx_[2] + bi_[2] + r_ * gh2);
            float hp = hl[b * 16 + cloc];
            float hn = (1.0f - z_) * n_2 + z_ * hp;
            hl[b * 16 + cloc] = hn;
            pack_store_h(hw, b, hn);
        }
    };

    auto gi_epi = [&](f32x4 (&acc)[3], float* gw) {
        #pragma unroll
        for (int g = 0; g < 3; ++g) {
            union { f32x4 v; u64 u[2]; } t; t.v = acc[g];
            float* dst = gw + ((size_t)g * NH + c) * NB + b0base;
            stu64(dst, t.u[0]);
            stu64(dst + 2, t.u[1]);
        }
    };

    // role-2 epilogue; optionally writes DETERMINISTIC fc partials to ypart[bc][b]
    auto gh_epi = [&](f32x4 (&acc)[3], const f32x4 gv[3], half_t* hw, float* ydst) {
        float hn4[4];
        #pragma unroll
        for (int q = 0; q < 4; ++q) {
            int b = b0base + q;
            float gh0 = acc[0][q] + bh_[0];
            float gh1 = acc[1][q] + bh_[1];
            float gh2 = acc[2][q] + bh_[2];
            float r_ = fast_sigmoid(gv[0][q] + bi_[0] + gh0);
            float z_ = fast_sigmoid(gv[1][q] + bi_[1] + gh1);
            float n_2 = fast_tanh(gv[2][q] + bi_[2] + r_ * gh2);
            float hp = hl[b * 16 + cloc];
            float hn = (1.0f - z_) * n_2 + z_ * hp;
            hl[b * 16 + cloc] = hn;
            hn4[q] = hn;
            pack_store_h(hw, b, hn);
        }
        if (ydst) {
            float s0 = hn4[0] * fcwv, s1 = hn4[1] * fcwv, s2 = hn4[2] * fcwv, s3 = hn4[3] * fcwv;
            #pragma unroll
            for (int m = 1; m < 16; m <<= 1) {   // deterministic butterfly over 16 cols
                s0 += __shfl_xor(s0, m); s1 += __shfl_xor(s1, m);
                s2 += __shfl_xor(s2, m); s3 += __shfl_xor(s3, m);
            }
            if (cloc == 0) {   // single writer per element: ypart[bc*NB + b]
                float* yp = ydst + bc * NB + b0base;
                stf32(yp,     s0);
                stf32(yp + 1, s1);
                stf32(yp + 2, s2);
                stf32(yp + 3, s3);
            }
        }
    };

    auto load_gi = [&](const float* gr, f32x4 (&gv)[3]) {
        #pragma unroll
        for (int g = 0; g < 3; ++g) {
            union { f32x4 v; u64 u[2]; } t;
            const float* src = gr + ((size_t)g * NH + c) * NB + b0base;
            t.u[0] = ldu64(src);
            t.u[1] = ldu64(src + 2);
            gv[g] = t.v;
        }
    };

    // deterministic y reduce: sum 64 partials per batch in fixed tree order, + fcb
    auto reduce_y = [&](float xv[4]) {
        float s[4];
        #pragma unroll
        for (int q = 0; q < 4; ++q) {
            float t0 = ldf32(p.ypart + (cloc * 4 + 0) * NB + b0base + q);
            float t1 = ldf32(p.ypart + (cloc * 4 + 1) * NB + b0base + q);
            float t2 = ldf32(p.ypart + (cloc * 4 + 2) * NB + b0base + q);
            float t3 = ldf32(p.ypart + (cloc * 4 + 3) * NB + b0base + q);
            s[q] = (t0 + t1) + (t2 + t3);
        }
        #pragma unroll
        for (int m = 1; m < 16; m <<= 1) {
            s[0] += __shfl_xor(s[0], m); s[1] += __shfl_xor(s[1], m);
            s[2] += __shfl_xor(s[2], m); s[3] += __shfl_xor(s[3], m);
        }
        #pragma unroll
        for (int q = 0; q < 4; ++q) xv[q] = s[q] + fcb_;
    };

    unsigned tgt = 0, ctgt = 0;
    int cur0 = 0, cur1 = 0, gcur = 0;
    f32x4 zero4 = {0.f, 0.f, 0.f, 0.f};
    float ysum[4] = {0.f, 0.f, 0.f, 0.f};   // role0: running sum of y0..y6

    auto COPY = [&]() {   // stage current read-buffers into region, return slot base
        ++ctgt;
        int slot = (int)(ctgt & 1);
        xcopy(cur0 ? p.h0b1 : p.h0b0, cur1 ? p.h1b1 : p.h1b0, slot);
        csync(ctgt);
        return (const char*)(p.reg + (size_t)(xcd_ * 2 + slot) * 524288);
    };

    // ---- conditioning: phases 0 .. NS+1 (3-stage pipeline); y0 partials at ph==NS+1
    for (int ph = 0; ph < NS + 2; ++ph) {
        float xv[4];
        f32x4 gv[3];
        if (role == 0 && ph < NS) {         // plain cached loads (x is read-only)
            #pragma unroll
            for (int q = 0; q < 4; ++q) xv[q] = p.x[(size_t)(b0base + q) * NS + ph];
        } else if (role == 2 && ph >= 2) {  // sc1 prefetch, hides under the copy
            load_gi(gcur ? p.gib1 : p.gib0, gv);
        }
        const char* regB = COPY();
        if (role == 0 && ph < NS) {
            f32x4 acc[3] = {zero4, zero4, zero4};
            do_gemm(regB, acc);
            l0_epi(xv, acc, cur0 ? p.h0b0 : p.h0b1);
        } else if (role == 1 && ph >= 1 && ph <= NS) {
            f32x4 acc[3] = {zero4, zero4, zero4};
            do_gemm(regB, acc);
            gi_epi(acc, gcur ? p.gib0 : p.gib1);
        } else if (role == 2 && ph >= 2) {
            f32x4 acc[3] = {zero4, zero4, zero4};
            do_gemm(regB + 262144, acc);
            gh_epi(acc, gv, cur1 ? p.h1b0 : p.h1b1, (ph == NS + 1) ? p.ypart : nullptr);
        }
        ++tgt; gbar(tgt);
        if (ph < NS) cur0 ^= 1;
        if (ph >= 1 && ph <= NS) gcur ^= 1;
        if (ph >= 2) cur1 ^= 1;
    }

    // ---- forecast: 7 autoregressive steps, 3 phases each (L0 -> GI -> GH+fc)
    for (int i = 1; i < NF; ++i) {
        float xv[4];
        if (role == 0) {                    // deterministic y_{i-1} reduce, then accumulate
            reduce_y(xv);
            #pragma unroll
            for (int q = 0; q < 4; ++q) ysum[q] += xv[q];
        }
        const char* regB = COPY();
        if (role == 0) {
            f32x4 acc[3] = {zero4, zero4, zero4};
            do_gemm(regB, acc);
            l0_epi(xv, acc, cur0 ? p.h0b0 : p.h0b1);
        }
        ++tgt; gbar(tgt); cur0 ^= 1;

        regB = COPY();
        if (role == 1) {
            f32x4 acc[3] = {zero4, zero4, zero4};
            do_gemm(regB, acc);
            gi_epi(acc, gcur ? p.gib0 : p.gib1);
        }
        ++tgt; gbar(tgt); gcur ^= 1;

        {
            f32x4 gv[3];
            if (role == 2) load_gi(gcur ? p.gib1 : p.gib0, gv);
            regB = COPY();
            if (role == 2) {
                f32x4 acc[3] = {zero4, zero4, zero4};
                do_gemm(regB + 262144, acc);
                gh_epi(acc, gv, cur1 ? p.h1b0 : p.h1b1, p.ypart);
            }
        }
        ++tgt; gbar(tgt); cur1 ^= 1;
    }

    // ---- final output: deterministic mean of forecasts + h_final export from LDS
    if (role == 0) {
        float y7[4];
        reduce_y(y7);   // y7 partials written in the last GH phase, gbar'd
        if (bid == 0 && cloc == 0) {
            #pragma unroll
            for (int q = 0; q < 4; ++q)
                p.out[b0base + q] = (ysum[q] + y7[q]) * 0.125f;
        }
    }
    if (role != 1) {
        float* ob = p.out + NB + (role == 2 ? (size_t)NB * NH : 0);
        for (int i = tid; i < NB * 16; i += NTH) {
            int b = i >> 4, cl = i & 15;
            ob[(size_t)b * NH + colbase + cl] = hl[i];
        }
    }
}

extern "C" void kernel_launch(void* const* d_in, const int* in_sizes, int n_in,
                              void* d_out, int out_size, void* d_ws, size_t ws_size,
                              hipStream_t stream)
{
    GP p;
    p.x    = (const float*)d_in[0];
    p.hin  = (const float*)d_in[1];
    p.Wih0 = (const float*)d_in[2];
    p.Whh0 = (const float*)d_in[3];
    p.bih0 = (const float*)d_in[4];
    p.bhh0 = (const float*)d_in[5];
    p.Wih1 = (const float*)d_in[6];
    p.Whh1 = (const float*)d_in[7];
    p.bih1 = (const float*)d_in[8];
    p.bhh1 = (const float*)d_in[9];
    p.fcw  = (const float*)d_in[10];
    p.fcb  = (const float*)d_in[11];
    p.out  = (float*)d_out;

    char* ws = (char*)d_ws;
    p.bar   = (unsigned*)ws;                     ws += 8192;
    p.h0b0  = (half_t*)ws;                       ws += 262144;
    p.h0b1  = (half_t*)ws;                       ws += 262144;
    p.h1b0  = (half_t*)ws;                       ws += 262144;
    p.h1b1  = (half_t*)ws;                       ws += 262144;
    p.gib0  = (float*)ws;                        ws += 1572864;
    p.gib1  = (float*)ws;                        ws += 1572864;
    p.ypart = (float*)ws;                        ws += 32768;   // 64 blocks x 128 batches f32
    ws = (char*)(((size_t)ws + 4095) & ~(size_t)4095);
    p.reg   = ws;                                ws += 8 * 2 * 524288;   // 8 MiB

    hipMemsetAsync(p.bar, 0, 8192, stream);
    k_init<<<512, 256, 0, stream>>>(p.hin, p.h0b0, p.h1b0);

    void* args[] = { &p };
    if (hipLaunchCooperativeKernel((void*)k_gru, dim3(NBLK), dim3(NTH), args,
                                   106752, stream) != hipSuccess) {
        (void)hipGetLastError();
        // fallback: 192 blocks @ ~104KiB LDS = 1 block/CU on 256 CUs -> co-resident
        k_gru<<<dim3(NBLK), dim3(NTH), 106752, stream>>>(p);
    }
}